// Round 8
// baseline (247.413 us; speedup 1.0000x reference)
//
#include <hip/hip_runtime.h>
#include <math.h>

#define TLEN 512
#define NB   1024
#define HSTR 80                 // h buf row stride (f16): 40 dwords -> <=2-way
#define HLAY (4 * HSTR)
#define XCH  64                 // timesteps per x chunk
#define XBSTR (XCH * 32 + 16)   // per-batch chunk stride (f16): +32B pad -> 8-dword bank shift
#define XHALF (4 * XBSTR)       // one chunk buffer (4 batches)

typedef _Float16 f16;
typedef f16   f16x4 __attribute__((ext_vector_type(4)));
typedef f16   f16x8 __attribute__((ext_vector_type(8)));
typedef float f32x4 __attribute__((ext_vector_type(4)));

__device__ __forceinline__ float sigf(float x) {
    return __builtin_amdgcn_rcpf(1.0f + __expf(-x));
}
__device__ __forceinline__ float tanhf_(float x) {
    return 2.0f * __builtin_amdgcn_rcpf(1.0f + __expf(-2.0f * x)) - 1.0f;
}
// compile-time-indexed select of v[g], g in 0..3 (3 cndmask, no scratch)
__device__ __forceinline__ float sel4(f32x4 v, int g) {
    float a = (g & 1) ? v[1] : v[0];
    float b = (g & 1) ? v[3] : v[2];
    return (g & 2) ? b : a;
}

// 256 blocks x 512 threads (8 waves, 2/SIMD). Block owns 4 batches.
// Waves 0-3: layer 0 of step it. Waves 4-7: layer 1 of step it-1 (pipelined).
// B-fragments are BROADCAST reads (lane bc reads batch bc&3); lane group G=bc>>2
// consumes acc reg r=G -> each lane owns ONE real (hidden,batch) cell in regs.
// x is staged through LDS in 64-step double-buffered chunks so the steady-state
// loop has ZERO global-memory ops (no vmcnt drain at the per-phase barriers).
__global__ __launch_bounds__(512, 2) void lstm_fused(
    const float* __restrict__ x,
    const float* __restrict__ Wih0, const float* __restrict__ Whh0,
    const float* __restrict__ bih0, const float* __restrict__ bhh0,
    const float* __restrict__ Wih1, const float* __restrict__ Whh1,
    const float* __restrict__ bih1, const float* __restrict__ bhh1,
    const float* __restrict__ fc1w, const float* __restrict__ fc1b,
    const float* __restrict__ fc2w, const float* __restrict__ fc2b,
    float* __restrict__ out)
{
    __shared__ __align__(16) f16 x_lds[2 * XHALF];    // ~33 KB
    __shared__ __align__(16) f16 h1buf[2 * HLAY];
    __shared__ __align__(16) f16 h2buf[2 * HLAY];
    __shared__ float zbuf[4][33];

    const int tid   = threadIdx.x;
    const int lane  = tid & 63;
    const int w     = tid >> 6;          // 0..7
    const int wg    = w & 3;             // hidden group within layer
    const bool isL0 = (w < 4);
    const int bc    = lane & 15;         // MFMA col / A-row-in-tile
    const int lq    = lane >> 4;         // k-octet / D-row quad
    const int G     = bc >> 2;           // copy-group -> acc reg this lane consumes
    const int b_own = bc & 3;            // batch this lane's column carries
    const int bg0   = blockIdx.x * 4;

    // ---- one-time: A-fragments for MY layer (4 gate tiles) ----
    f16x8 A[4][4];
    float bsv[4];
    #pragma unroll
    for (int g = 0; g < 4; ++g) {
        const int gr = g * 64 + 16 * wg + bc;
        #pragma unroll
        for (int s = 0; s < 4; ++s) {
            #pragma unroll
            for (int i = 0; i < 8; ++i) {
                int k = 32 * s + lq * 8 + i;
                float v = 0.0f;
                if (isL0) {
                    if (s < 3) v = (k < 32) ? Wih0[gr * 32 + k] : Whh0[gr * 64 + (k - 32)];
                } else {
                    v = (k < 64) ? Wih1[gr * 64 + k] : Whh1[gr * 64 + (k - 64)];
                }
                A[g][s][i] = (f16)v;
            }
        }
        const int gd = g * 64 + 16 * wg + 4 * lq + G;   // my cell's gate row
        bsv[g] = isL0 ? (bih0[gd] + bhh0[gd]) : (bih1[gd] + bhh1[gd]);
    }

    // ---- zero h LDS ----
    for (int i = tid; i < 2 * HLAY; i += 512) { h1buf[i] = (f16)0; h2buf[i] = (f16)0; }

    // chunk refill: load timesteps [64ch, 64ch+64) of the block's 4 batches into
    // x_lds buffer parity ch&1. All 512 threads: 4 float4 each, coalesced.
    const int rf_b   = tid >> 7;         // 0..3
    const int rf_rem = tid & 127;
#define REFILL(ch)                                                            \
    {                                                                         \
        f16* dst = x_lds + ((ch) & 1) * XHALF + rf_b * XBSTR;                 \
        const float4* src = (const float4*)(x +                               \
            ((long)(bg0 + rf_b) * TLEN + (ch) * XCH) * 32);                   \
        float4 v0 = src[rf_rem];                                              \
        float4 v1 = src[rf_rem + 128];                                        \
        float4 v2 = src[rf_rem + 256];                                        \
        float4 v3 = src[rf_rem + 384];                                        \
        f16x4 h;                                                              \
        h[0]=(f16)v0.x; h[1]=(f16)v0.y; h[2]=(f16)v0.z; h[3]=(f16)v0.w;       \
        *(f16x4*)(dst + (rf_rem)       * 4) = h;                              \
        h[0]=(f16)v1.x; h[1]=(f16)v1.y; h[2]=(f16)v1.z; h[3]=(f16)v1.w;       \
        *(f16x4*)(dst + (rf_rem + 128) * 4) = h;                              \
        h[0]=(f16)v2.x; h[1]=(f16)v2.y; h[2]=(f16)v2.z; h[3]=(f16)v2.w;       \
        *(f16x4*)(dst + (rf_rem + 256) * 4) = h;                              \
        h[0]=(f16)v3.x; h[1]=(f16)v3.y; h[2]=(f16)v3.z; h[3]=(f16)v3.w;       \
        *(f16x4*)(dst + (rf_rem + 384) * 4) = h;                              \
    }

    REFILL(0)                       // chunk 0 -> parity 0
    __syncthreads();

    const int bch = b_own * HSTR + lq * 8;                 // broadcast h B-frag offset
    const int bxx = b_own * XBSTR + lq * 8;                // x B-frag offset (within buffer)
    const int hwr = b_own * HSTR + 16 * wg + 4 * lq + G;   // h write

    float cst = 0.0f;   // cell state of my (16wg+4lq+G, b_own)

#define CELL_UPDATE(HBUF, PW)                                                 \
    {                                                                         \
        float pi = sel4(a0, G) + bsv[0];                                      \
        float pf = sel4(a1, G) + bsv[1];                                      \
        float pg = sel4(a2, G) + bsv[2];                                      \
        float po = sel4(a3, G) + bsv[3];                                      \
        float iv = sigf(pi), fv = sigf(pf);                                   \
        float gv = tanhf_(pg), ov = sigf(po);                                 \
        cst = fmaf(fv, cst, iv * gv);                                         \
        HBUF[(PW) * HLAY + hwr] = (f16)(ov * tanhf_(cst));                    \
    }

// L0 at iteration it (parity p = it&1): reads x_lds chunk (it>>6), h1buf[p^1];
// writes h1buf[p].
#define L0_PHASE(p, itv)                                                      \
    {                                                                         \
        f16x8 b0 = *(const f16x8*)(x_lds + (((itv) >> 6) & 1) * XHALF +       \
                                   ((itv) & (XCH - 1)) * 32 + bxx);           \
        f16x8 b1 = *(const f16x8*)(h1buf + ((p)^1) * HLAY + bch);             \
        f16x8 b2 = *(const f16x8*)(h1buf + ((p)^1) * HLAY + bch + 32);        \
        f32x4 a0 = {0.f,0.f,0.f,0.f}, a1 = a0, a2 = a0, a3 = a0;              \
        a0 = __builtin_amdgcn_mfma_f32_16x16x32_f16(A[0][0], b0, a0, 0,0,0);  \
        a1 = __builtin_amdgcn_mfma_f32_16x16x32_f16(A[1][0], b0, a1, 0,0,0);  \
        a2 = __builtin_amdgcn_mfma_f32_16x16x32_f16(A[2][0], b0, a2, 0,0,0);  \
        a3 = __builtin_amdgcn_mfma_f32_16x16x32_f16(A[3][0], b0, a3, 0,0,0);  \
        a0 = __builtin_amdgcn_mfma_f32_16x16x32_f16(A[0][1], b1, a0, 0,0,0);  \
        a1 = __builtin_amdgcn_mfma_f32_16x16x32_f16(A[1][1], b1, a1, 0,0,0);  \
        a2 = __builtin_amdgcn_mfma_f32_16x16x32_f16(A[2][1], b1, a2, 0,0,0);  \
        a3 = __builtin_amdgcn_mfma_f32_16x16x32_f16(A[3][1], b1, a3, 0,0,0);  \
        a0 = __builtin_amdgcn_mfma_f32_16x16x32_f16(A[0][2], b2, a0, 0,0,0);  \
        a1 = __builtin_amdgcn_mfma_f32_16x16x32_f16(A[1][2], b2, a1, 0,0,0);  \
        a2 = __builtin_amdgcn_mfma_f32_16x16x32_f16(A[2][2], b2, a2, 0,0,0);  \
        a3 = __builtin_amdgcn_mfma_f32_16x16x32_f16(A[3][2], b2, a3, 0,0,0);  \
        CELL_UPDATE(h1buf, p)                                                 \
    }

// L1 at iteration it (t = it-1, p = it&1): reads h1buf[p^1] (=h1[t]),
// h2buf[p] (=h2[t-1]); writes h2buf[p^1] (=h2[t]).
#define L1_PHASE(p)                                                           \
    {                                                                         \
        f16x8 b0 = *(const f16x8*)(h1buf + ((p)^1) * HLAY + bch);             \
        f16x8 b1 = *(const f16x8*)(h1buf + ((p)^1) * HLAY + bch + 32);        \
        f16x8 b2 = *(const f16x8*)(h2buf + (p) * HLAY + bch);                 \
        f16x8 b3 = *(const f16x8*)(h2buf + (p) * HLAY + bch + 32);            \
        f32x4 a0 = {0.f,0.f,0.f,0.f}, a1 = a0, a2 = a0, a3 = a0;              \
        a0 = __builtin_amdgcn_mfma_f32_16x16x32_f16(A[0][0], b0, a0, 0,0,0);  \
        a1 = __builtin_amdgcn_mfma_f32_16x16x32_f16(A[1][0], b0, a1, 0,0,0);  \
        a2 = __builtin_amdgcn_mfma_f32_16x16x32_f16(A[2][0], b0, a2, 0,0,0);  \
        a3 = __builtin_amdgcn_mfma_f32_16x16x32_f16(A[3][0], b0, a3, 0,0,0);  \
        a0 = __builtin_amdgcn_mfma_f32_16x16x32_f16(A[0][1], b1, a0, 0,0,0);  \
        a1 = __builtin_amdgcn_mfma_f32_16x16x32_f16(A[1][1], b1, a1, 0,0,0);  \
        a2 = __builtin_amdgcn_mfma_f32_16x16x32_f16(A[2][1], b1, a2, 0,0,0);  \
        a3 = __builtin_amdgcn_mfma_f32_16x16x32_f16(A[3][1], b1, a3, 0,0,0);  \
        a0 = __builtin_amdgcn_mfma_f32_16x16x32_f16(A[0][2], b2, a0, 0,0,0);  \
        a1 = __builtin_amdgcn_mfma_f32_16x16x32_f16(A[1][2], b2, a1, 0,0,0);  \
        a2 = __builtin_amdgcn_mfma_f32_16x16x32_f16(A[2][2], b2, a2, 0,0,0);  \
        a3 = __builtin_amdgcn_mfma_f32_16x16x32_f16(A[3][2], b2, a3, 0,0,0);  \
        a0 = __builtin_amdgcn_mfma_f32_16x16x32_f16(A[0][3], b3, a0, 0,0,0);  \
        a1 = __builtin_amdgcn_mfma_f32_16x16x32_f16(A[1][3], b3, a1, 0,0,0);  \
        a2 = __builtin_amdgcn_mfma_f32_16x16x32_f16(A[2][3], b3, a2, 0,0,0);  \
        a3 = __builtin_amdgcn_mfma_f32_16x16x32_f16(A[3][3], b3, a3, 0,0,0);  \
        CELL_UPDATE(h2buf, (p)^1)                                             \
    }

    // ---- pipeline: it = 0 .. 512 ----
    if (isL0) L0_PHASE(0, 0)            // it = 0
    REFILL(1)                           // chunk 1 -> parity 1 (reads start at it=64)
    __syncthreads();

    #pragma unroll 1
    for (int k = 0; k < 255; ++k) {     // it = 2k+1, 2k+2  (1..510)
        if (isL0) L0_PHASE(1, 2 * k + 1) else L1_PHASE(1)
        __syncthreads();
        const int it2 = 2 * k + 2;
        if (isL0) L0_PHASE(0, it2) else L1_PHASE(0)
        if ((it2 & (XCH - 1)) == 0 && it2 <= TLEN - 2 * XCH)
            REFILL((it2 >> 6) + 1)      // chunk c+1 at it=64c (c=1..6)
        __syncthreads();
    }

    if (isL0) L0_PHASE(1, 511) else L1_PHASE(1)   // it = 511
    __syncthreads();
    if (!isL0) L1_PHASE(0)                        // it = 512 (L1 finishes h2[511])
    __syncthreads();

#undef L0_PHASE
#undef L1_PHASE
#undef CELL_UPDATE
#undef REFILL

    // ---- FC head: h2[511] is in parity 1 ----
    const f16* h2f = h2buf + HLAY;
    if (tid < 128) {
        int b = tid >> 5, m = tid & 31;
        float z = fc1b[m];
        #pragma unroll
        for (int j = 0; j < 64; ++j)
            z = fmaf(fc1w[m * 64 + j], (float)h2f[b * HSTR + j], z);
        zbuf[b][m] = fmaxf(z, 0.0f);
    }
    __syncthreads();
    if (tid < 8) {
        int b = tid >> 1, o = tid & 1;
        float s = fc2b[o];
        #pragma unroll
        for (int m = 0; m < 32; ++m)
            s = fmaf(fc2w[o * 32 + m], zbuf[b][m], s);
        out[(long)(bg0 + b) * 2 + o] = s;
    }
}

extern "C" void kernel_launch(void* const* d_in, const int* in_sizes, int n_in,
                              void* d_out, int out_size, void* d_ws, size_t ws_size,
                              hipStream_t stream) {
    const float* x    = (const float*)d_in[0];
    const float* Wih0 = (const float*)d_in[1];
    const float* Whh0 = (const float*)d_in[2];
    const float* bih0 = (const float*)d_in[3];
    const float* bhh0 = (const float*)d_in[4];
    const float* Wih1 = (const float*)d_in[5];
    const float* Whh1 = (const float*)d_in[6];
    const float* bih1 = (const float*)d_in[7];
    const float* bhh1 = (const float*)d_in[8];
    const float* fc1w = (const float*)d_in[9];
    const float* fc1b = (const float*)d_in[10];
    const float* fc2w = (const float*)d_in[11];
    const float* fc2b = (const float*)d_in[12];
    float* out = (float*)d_out;

    lstm_fused<<<dim3(NB / 4), dim3(512), 0, stream>>>(
        x, Wih0, Whh0, bih0, bhh0, Wih1, Whh1, bih1, bhh1,
        fc1w, fc1b, fc2w, fc2b, out);
}

// Round 9
// 227.413 us; speedup vs baseline: 1.0879x; 1.0879x over previous
//
#include <hip/hip_runtime.h>
#include <math.h>

#define TLEN 512
#define NB   1024
#define HSTR 80                 // h buf row stride (f16): 40 dwords -> <=2-way
#define HLAY (4 * HSTR)
#define XCH  64                 // timesteps per x chunk
#define XBSTR (XCH * 32 + 16)   // per-batch chunk stride (f16)
#define XHALF (4 * XBSTR)       // one chunk buffer (4 batches)

#define NLOG2E  (-1.44269504f)  // -log2(e): sigmoid gates
#define N2LOG2E (-2.88539008f)  // -2log2(e): tanh gate / tanh(c)

typedef _Float16 f16;
typedef f16   f16x4 __attribute__((ext_vector_type(4)));
typedef f16   f16x8 __attribute__((ext_vector_type(8)));
typedef float f32x4 __attribute__((ext_vector_type(4)));

__device__ __forceinline__ float ex2(float x) {
#if __has_builtin(__builtin_amdgcn_exp2f)
    return __builtin_amdgcn_exp2f(x);
#else
    return exp2f(x);
#endif
}
__device__ __forceinline__ float rcp_(float x) { return __builtin_amdgcn_rcpf(x); }
// compile-time-indexed select of v[g], g in 0..3 (3 cndmask, no scratch)
__device__ __forceinline__ float sel4(f32x4 v, int g) {
    float a = (g & 1) ? v[1] : v[0];
    float b = (g & 1) ? v[3] : v[2];
    return (g & 2) ? b : a;
}

// 256 blocks x 512 threads (8 waves, 2/SIMD: one L0 + one L1 wave).
// Waves 0-3: layer 0 of step it; waves 4-7: layer 1 of step it-1 (pipelined).
// Broadcast B-reads (lane bc reads batch bc&3); copy-group G=bc>>2 consumes acc
// reg r=G -> each lane owns ONE (hidden,batch) cell entirely in registers.
// Weights pre-scaled by -log2e (-2log2e for tanh gate) so activations are
// rcp(1+exp2(v)) with zero negate/mul; biases ride in the MFMA C operand.
__global__ __launch_bounds__(512, 2) void lstm_fused(
    const float* __restrict__ x,
    const float* __restrict__ Wih0, const float* __restrict__ Whh0,
    const float* __restrict__ bih0, const float* __restrict__ bhh0,
    const float* __restrict__ Wih1, const float* __restrict__ Whh1,
    const float* __restrict__ bih1, const float* __restrict__ bhh1,
    const float* __restrict__ fc1w, const float* __restrict__ fc1b,
    const float* __restrict__ fc2w, const float* __restrict__ fc2b,
    float* __restrict__ out)
{
    __shared__ __align__(16) f16 x_lds[2 * XHALF];    // ~33 KB
    __shared__ __align__(16) f16 h1buf[2 * HLAY];
    __shared__ __align__(16) f16 h2buf[2 * HLAY];
    __shared__ float zbuf[4][33];

    const int tid   = threadIdx.x;
    const int lane  = tid & 63;
    const int w     = tid >> 6;          // 0..7
    const int wg    = w & 3;             // hidden group within layer
    const bool isL0 = (w < 4);
    const int bc    = lane & 15;         // MFMA col / A-row-in-tile
    const int lq    = lane >> 4;         // k-octet / D-row quad
    const int G     = bc >> 2;           // copy-group -> acc reg this lane consumes
    const int b_own = bc & 3;            // batch this lane's column carries
    const int bg0   = blockIdx.x * 4;

    // ---- one-time: pre-scaled A-fragments + bias C-init vectors ----
    const float wsc[4] = {NLOG2E, NLOG2E, N2LOG2E, NLOG2E};
    f16x8 A[4][4];
    f32x4 cb[4];
    #pragma unroll
    for (int g = 0; g < 4; ++g) {
        const int gr = g * 64 + 16 * wg + bc;
        #pragma unroll
        for (int s = 0; s < 4; ++s) {
            #pragma unroll
            for (int i = 0; i < 8; ++i) {
                int k = 32 * s + lq * 8 + i;
                float v = 0.0f;
                if (isL0) {
                    if (s < 3) v = (k < 32) ? Wih0[gr * 32 + k] : Whh0[gr * 64 + (k - 32)];
                } else {
                    v = (k < 64) ? Wih1[gr * 64 + k] : Whh1[gr * 64 + (k - 64)];
                }
                A[g][s][i] = (f16)(v * wsc[g]);
            }
        }
        #pragma unroll
        for (int r = 0; r < 4; ++r) {
            const int gd = g * 64 + 16 * wg + 4 * lq + r;   // D-row gate index
            float bb = isL0 ? (bih0[gd] + bhh0[gd]) : (bih1[gd] + bhh1[gd]);
            cb[g][r] = bb * wsc[g];
        }
    }

    // ---- zero h LDS ----
    for (int i = tid; i < 2 * HLAY; i += 512) { h1buf[i] = (f16)0; h2buf[i] = (f16)0; }

    // chunk refill: timesteps [64ch, 64ch+64) of 4 batches -> x_lds parity ch&1.
    const int rf_b   = tid >> 7;         // 0..3
    const int rf_rem = tid & 127;
#define REFILL(ch)                                                            \
    {                                                                         \
        f16* dst = x_lds + ((ch) & 1) * XHALF + rf_b * XBSTR;                 \
        const float4* src = (const float4*)(x +                               \
            ((long)(bg0 + rf_b) * TLEN + (ch) * XCH) * 32);                   \
        float4 v0 = src[rf_rem];                                              \
        float4 v1 = src[rf_rem + 128];                                        \
        float4 v2 = src[rf_rem + 256];                                        \
        float4 v3 = src[rf_rem + 384];                                        \
        f16x4 h;                                                              \
        h[0]=(f16)v0.x; h[1]=(f16)v0.y; h[2]=(f16)v0.z; h[3]=(f16)v0.w;       \
        *(f16x4*)(dst + (rf_rem)       * 4) = h;                              \
        h[0]=(f16)v1.x; h[1]=(f16)v1.y; h[2]=(f16)v1.z; h[3]=(f16)v1.w;       \
        *(f16x4*)(dst + (rf_rem + 128) * 4) = h;                              \
        h[0]=(f16)v2.x; h[1]=(f16)v2.y; h[2]=(f16)v2.z; h[3]=(f16)v2.w;       \
        *(f16x4*)(dst + (rf_rem + 256) * 4) = h;                              \
        h[0]=(f16)v3.x; h[1]=(f16)v3.y; h[2]=(f16)v3.z; h[3]=(f16)v3.w;       \
        *(f16x4*)(dst + (rf_rem + 384) * 4) = h;                              \
    }

    REFILL(0)                       // chunk 0 -> parity 0
    __syncthreads();

    const int bch = b_own * HSTR + lq * 8;                 // broadcast h B-frag offset
    const int bxx = b_own * XBSTR + lq * 8;                // x B-frag offset
    const int hwr = b_own * HSTR + 16 * wg + 4 * lq + G;   // h write

    float cst = 0.0f;   // cell state of my (16wg+4lq+G, b_own)

#define CELL_UPDATE(HBUF, PW)                                                 \
    {                                                                         \
        float pi = sel4(a0, G);                                               \
        float pf = sel4(a1, G);                                               \
        float pg = sel4(a2, G);                                               \
        float po = sel4(a3, G);                                               \
        float iv = rcp_(1.0f + ex2(pi));                                      \
        float fv = rcp_(1.0f + ex2(pf));                                      \
        float gv = fmaf(2.0f, rcp_(1.0f + ex2(pg)), -1.0f);                   \
        float ov = rcp_(1.0f + ex2(po));                                      \
        cst = fmaf(fv, cst, iv * gv);                                         \
        float tc = fmaf(2.0f, rcp_(1.0f + ex2(cst * N2LOG2E)), -1.0f);        \
        HBUF[(PW) * HLAY + hwr] = (f16)(ov * tc);                             \
    }

// L0 at iteration it (parity p = it&1): reads x_lds chunk (it>>6), h1buf[p^1];
// writes h1buf[p].
#define L0_PHASE(p, itv)                                                      \
    {                                                                         \
        f16x8 b0 = *(const f16x8*)(x_lds + (((itv) >> 6) & 1) * XHALF +       \
                                   ((itv) & (XCH - 1)) * 32 + bxx);           \
        f16x8 b1 = *(const f16x8*)(h1buf + ((p)^1) * HLAY + bch);             \
        f16x8 b2 = *(const f16x8*)(h1buf + ((p)^1) * HLAY + bch + 32);        \
        __builtin_amdgcn_s_setprio(1);                                        \
        f32x4 a0 = __builtin_amdgcn_mfma_f32_16x16x32_f16(A[0][0], b0, cb[0], 0,0,0); \
        f32x4 a1 = __builtin_amdgcn_mfma_f32_16x16x32_f16(A[1][0], b0, cb[1], 0,0,0); \
        f32x4 a2 = __builtin_amdgcn_mfma_f32_16x16x32_f16(A[2][0], b0, cb[2], 0,0,0); \
        f32x4 a3 = __builtin_amdgcn_mfma_f32_16x16x32_f16(A[3][0], b0, cb[3], 0,0,0); \
        a0 = __builtin_amdgcn_mfma_f32_16x16x32_f16(A[0][1], b1, a0, 0,0,0);  \
        a1 = __builtin_amdgcn_mfma_f32_16x16x32_f16(A[1][1], b1, a1, 0,0,0);  \
        a2 = __builtin_amdgcn_mfma_f32_16x16x32_f16(A[2][1], b1, a2, 0,0,0);  \
        a3 = __builtin_amdgcn_mfma_f32_16x16x32_f16(A[3][1], b1, a3, 0,0,0);  \
        a0 = __builtin_amdgcn_mfma_f32_16x16x32_f16(A[0][2], b2, a0, 0,0,0);  \
        a1 = __builtin_amdgcn_mfma_f32_16x16x32_f16(A[1][2], b2, a1, 0,0,0);  \
        a2 = __builtin_amdgcn_mfma_f32_16x16x32_f16(A[2][2], b2, a2, 0,0,0);  \
        a3 = __builtin_amdgcn_mfma_f32_16x16x32_f16(A[3][2], b2, a3, 0,0,0);  \
        __builtin_amdgcn_s_setprio(0);                                        \
        CELL_UPDATE(h1buf, p)                                                 \
    }

// L1 at iteration it (t = it-1, p = it&1): reads h1buf[p^1] (=h1[t]),
// h2buf[p] (=h2[t-1]); writes h2buf[p^1] (=h2[t]).
#define L1_PHASE(p)                                                           \
    {                                                                         \
        f16x8 b0 = *(const f16x8*)(h1buf + ((p)^1) * HLAY + bch);             \
        f16x8 b1 = *(const f16x8*)(h1buf + ((p)^1) * HLAY + bch + 32);        \
        f16x8 b2 = *(const f16x8*)(h2buf + (p) * HLAY + bch);                 \
        f16x8 b3 = *(const f16x8*)(h2buf + (p) * HLAY + bch + 32);            \
        __builtin_amdgcn_s_setprio(1);                                        \
        f32x4 a0 = __builtin_amdgcn_mfma_f32_16x16x32_f16(A[0][0], b0, cb[0], 0,0,0); \
        f32x4 a1 = __builtin_amdgcn_mfma_f32_16x16x32_f16(A[1][0], b0, cb[1], 0,0,0); \
        f32x4 a2 = __builtin_amdgcn_mfma_f32_16x16x32_f16(A[2][0], b0, cb[2], 0,0,0); \
        f32x4 a3 = __builtin_amdgcn_mfma_f32_16x16x32_f16(A[3][0], b0, cb[3], 0,0,0); \
        a0 = __builtin_amdgcn_mfma_f32_16x16x32_f16(A[0][1], b1, a0, 0,0,0);  \
        a1 = __builtin_amdgcn_mfma_f32_16x16x32_f16(A[1][1], b1, a1, 0,0,0);  \
        a2 = __builtin_amdgcn_mfma_f32_16x16x32_f16(A[2][1], b1, a2, 0,0,0);  \
        a3 = __builtin_amdgcn_mfma_f32_16x16x32_f16(A[3][1], b1, a3, 0,0,0);  \
        a0 = __builtin_amdgcn_mfma_f32_16x16x32_f16(A[0][2], b2, a0, 0,0,0);  \
        a1 = __builtin_amdgcn_mfma_f32_16x16x32_f16(A[1][2], b2, a1, 0,0,0);  \
        a2 = __builtin_amdgcn_mfma_f32_16x16x32_f16(A[2][2], b2, a2, 0,0,0);  \
        a3 = __builtin_amdgcn_mfma_f32_16x16x32_f16(A[3][2], b2, a3, 0,0,0);  \
        a0 = __builtin_amdgcn_mfma_f32_16x16x32_f16(A[0][3], b3, a0, 0,0,0);  \
        a1 = __builtin_amdgcn_mfma_f32_16x16x32_f16(A[1][3], b3, a1, 0,0,0);  \
        a2 = __builtin_amdgcn_mfma_f32_16x16x32_f16(A[2][3], b3, a2, 0,0,0);  \
        a3 = __builtin_amdgcn_mfma_f32_16x16x32_f16(A[3][3], b3, a3, 0,0,0);  \
        __builtin_amdgcn_s_setprio(0);                                        \
        CELL_UPDATE(h2buf, (p)^1)                                             \
    }

    // ---- pipeline: it = 0 .. 512 ----
    if (isL0) L0_PHASE(0, 0)            // it = 0
    REFILL(1)                           // chunk 1 -> parity 1 (reads start at it=64)
    __syncthreads();

    #pragma unroll 1
    for (int k = 0; k < 255; ++k) {     // it = 2k+1, 2k+2  (1..510)
        if (isL0) L0_PHASE(1, 2 * k + 1) else L1_PHASE(1)
        __syncthreads();
        const int it2 = 2 * k + 2;
        if (isL0) L0_PHASE(0, it2) else L1_PHASE(0)
        if ((it2 & (XCH - 1)) == 0 && it2 <= TLEN - 2 * XCH)
            REFILL((it2 >> 6) + 1)      // chunk c+1 at it=64c (c=1..6)
        __syncthreads();
    }

    if (isL0) L0_PHASE(1, 511) else L1_PHASE(1)   // it = 511
    __syncthreads();
    if (!isL0) L1_PHASE(0)                        // it = 512 (L1 finishes h2[511])
    __syncthreads();

#undef L0_PHASE
#undef L1_PHASE
#undef CELL_UPDATE
#undef REFILL

    // ---- FC head: h2[511] is in parity 1 ----
    const f16* h2f = h2buf + HLAY;
    if (tid < 128) {
        int b = tid >> 5, m = tid & 31;
        float z = fc1b[m];
        #pragma unroll
        for (int j = 0; j < 64; ++j)
            z = fmaf(fc1w[m * 64 + j], (float)h2f[b * HSTR + j], z);
        zbuf[b][m] = fmaxf(z, 0.0f);
    }
    __syncthreads();
    if (tid < 8) {
        int b = tid >> 1, o = tid & 1;
        float s = fc2b[o];
        #pragma unroll
        for (int m = 0; m < 32; ++m)
            s = fmaf(fc2w[o * 32 + m], zbuf[b][m], s);
        out[(long)(bg0 + b) * 2 + o] = s;
    }
}

extern "C" void kernel_launch(void* const* d_in, const int* in_sizes, int n_in,
                              void* d_out, int out_size, void* d_ws, size_t ws_size,
                              hipStream_t stream) {
    const float* x    = (const float*)d_in[0];
    const float* Wih0 = (const float*)d_in[1];
    const float* Whh0 = (const float*)d_in[2];
    const float* bih0 = (const float*)d_in[3];
    const float* bhh0 = (const float*)d_in[4];
    const float* Wih1 = (const float*)d_in[5];
    const float* Whh1 = (const float*)d_in[6];
    const float* bih1 = (const float*)d_in[7];
    const float* bhh1 = (const float*)d_in[8];
    const float* fc1w = (const float*)d_in[9];
    const float* fc1b = (const float*)d_in[10];
    const float* fc2w = (const float*)d_in[11];
    const float* fc2b = (const float*)d_in[12];
    float* out = (float*)d_out;

    lstm_fused<<<dim3(NB / 4), dim3(512), 0, stream>>>(
        x, Wih0, Whh0, bih0, bhh0, Wih1, Whh1, bih1, bhh1,
        fc1w, fc1b, fc2w, fc2b, out);
}